// Round 1
// baseline (85.063 us; speedup 1.0000x reference)
//
#include <hip/hip_runtime.h>

#define NBINS 40
#define TLEN  200
#define NFEAT 42
#define H1    128
#define H2    64
#define NE    3

// One thread per sample. 256 threads/block, grid = B/256.
__global__ __launch_bounds__(256, 1)
void gating_fused(const int* __restrict__ x,
                  const float* __restrict__ W1, const float* __restrict__ b1,
                  const float* __restrict__ W2, const float* __restrict__ b2,
                  const float* __restrict__ W3, const float* __restrict__ b3,
                  float* __restrict__ out)
{
    // 4 u8 sub-histograms per thread (one per int4 slot): [sub][bin][tid] bytes.
    // 4*40*256 = 40960 B = 40 KB. Per-sub counts <= 50 -> fits u8.
    __shared__ uint32_t h32[4 * NBINS * 256 / 4]; // 10240 words
    unsigned char* hb = reinterpret_cast<unsigned char*>(h32);

    const int tid = threadIdx.x;
    const size_t b = (size_t)blockIdx.x * 256 + tid;

    // zero my histogram bytes (each thread owns byte lane `tid` of every word-row)
    #pragma unroll
    for (int w = 0; w < 40; ++w) h32[w * 256 + tid] = 0u;
    // no barrier: histograms are thread-private

    // ---- histogram over 200 tokens, depth-3 software pipeline ----
    const int4* xrow = reinterpret_cast<const int4*>(x + b * TLEN);
    int4 p0 = xrow[0], p1 = xrow[1], p2 = xrow[2];
    for (int it = 0; it < TLEN / 4; ++it) {
        int4 cur = p0; p0 = p1; p1 = p2;
        int nxt = it + 3; nxt = (nxt < TLEN / 4) ? nxt : (TLEN / 4 - 1);
        p2 = xrow[nxt];
        const int t0 = cur.x, t1 = cur.y, t2 = cur.z, t3 = cur.w;
        const int i0 = (0 * NBINS + t0) * 256 + tid;
        const int i1 = (1 * NBINS + t1) * 256 + tid;
        const int i2 = (2 * NBINS + t2) * 256 + tid;
        const int i3 = (3 * NBINS + t3) * 256 + tid;
        // 4 independent RMW chains (different sub-histograms)
        unsigned char c0 = hb[i0], c1 = hb[i1], c2 = hb[i2], c3 = hb[i3];
        hb[i0] = (unsigned char)(c0 + (t0 != 0));
        hb[i1] = (unsigned char)(c1 + (t1 != 0));
        hb[i2] = (unsigned char)(c2 + (t2 != 0));
        hb[i3] = (unsigned char)(c3 + (t3 != 0));
    }

    // ---- gather features into registers ----
    float f[NFEAT];
    uint32_t total = 0, uniq = 0;
    #pragma unroll
    for (int c = 0; c < NBINS; ++c) {
        uint32_t s = (uint32_t)hb[(0 * NBINS + c) * 256 + tid]
                   + (uint32_t)hb[(1 * NBINS + c) * 256 + tid]
                   + (uint32_t)hb[(2 * NBINS + c) * 256 + tid]
                   + (uint32_t)hb[(3 * NBINS + c) * 256 + tid];
        f[2 + c] = (float)s;
        total += s;
        uniq += (s != 0u) ? 1u : 0u;
    }
    f[0] = (float)total;  // seq_len (pad tokens never counted)
    f[1] = (float)uniq;   // unique_chars (bin 0 always zero)

    // ---- layer1 (42->128) chunked by 8, fused into layer2 (128->64) accum ----
    float acc2[H2];
    #pragma unroll
    for (int k = 0; k < H2; ++k) acc2[k] = b2[k];

    for (int jc = 0; jc < H1 / 8; ++jc) {   // runtime loop: W indices wave-uniform
        float a[8];
        #pragma unroll
        for (int u = 0; u < 8; ++u) a[u] = b1[jc * 8 + u];
        #pragma unroll
        for (int i = 0; i < NFEAT; ++i) {
            const float fi = f[i];
            #pragma unroll
            for (int u = 0; u < 8; ++u)
                a[u] = fmaf(fi, W1[i * H1 + jc * 8 + u], a[u]);
        }
        #pragma unroll
        for (int u = 0; u < 8; ++u) {
            const float h = fmaxf(a[u], 0.0f);
            #pragma unroll
            for (int k = 0; k < H2; ++k)
                acc2[k] = fmaf(h, W2[(jc * 8 + u) * H2 + k], acc2[k]);
        }
    }

    // ---- layer3 (64->3) + softmax ----
    float lg[NE];
    #pragma unroll
    for (int e = 0; e < NE; ++e) lg[e] = b3[e];
    #pragma unroll
    for (int k = 0; k < H2; ++k) {
        const float h = fmaxf(acc2[k], 0.0f);
        #pragma unroll
        for (int e = 0; e < NE; ++e)
            lg[e] = fmaf(h, W3[k * NE + e], lg[e]);
    }
    const float m  = fmaxf(lg[0], fmaxf(lg[1], lg[2]));
    const float e0 = __expf(lg[0] - m);
    const float e1 = __expf(lg[1] - m);
    const float e2 = __expf(lg[2] - m);
    const float inv = 1.0f / (e0 + e1 + e2);
    out[b * 3 + 0] = e0 * inv;
    out[b * 3 + 1] = e1 * inv;
    out[b * 3 + 2] = e2 * inv;
}

extern "C" void kernel_launch(void* const* d_in, const int* in_sizes, int n_in,
                              void* d_out, int out_size, void* d_ws, size_t ws_size,
                              hipStream_t stream) {
    const int*   x  = (const int*)d_in[0];
    const float* W1 = (const float*)d_in[1];
    const float* b1 = (const float*)d_in[2];
    const float* W2 = (const float*)d_in[3];
    const float* b2 = (const float*)d_in[4];
    const float* W3 = (const float*)d_in[5];
    const float* b3 = (const float*)d_in[6];
    float* out = (float*)d_out;

    const int B = in_sizes[0] / TLEN;   // 65536
    gating_fused<<<B / 256, 256, 0, stream>>>(x, W1, b1, W2, b2, W3, b3, out);
}